// Round 10
// baseline (117.062 us; speedup 1.0000x reference)
//
#include <hip/hip_runtime.h>
#include <float.h>

typedef float f32x4 __attribute__((ext_vector_type(4)));  // native vec for NT ops

// Problem constants (B=64, S=16, N=256, T=256, D=500, NUM_FRAMES=16, TOPK=3)
static constexpr long OUT0 = 0;          // props_feats  (1024, 16, 500)  = 8,192,000
static constexpr long OUT1 = 8192000;    // overlaps     (64,16,256,256)  = 67,108,864
static constexpr long OUT2 = 75300864;   // max_timestamps (64,16,3,2)    = 6,144
static constexpr long OUT3 = 75307008;   // max_scores   (64,16,3)        = 3,072

// Streaming-phase insert: ids strictly increase within a thread, so the
// lax.top_k tie-break (equal value -> smaller index) is automatic.
__device__ __forceinline__ void insert_stream(float v, int id, float tv[3], int ti[3]) {
  if (v > tv[2]) {
    if (v > tv[0]) {
      tv[2] = tv[1]; ti[2] = ti[1];
      tv[1] = tv[0]; ti[1] = ti[0];
      tv[0] = v;     ti[0] = id;
    } else if (v > tv[1]) {
      tv[2] = tv[1]; ti[2] = ti[1];
      tv[1] = v;     ti[1] = id;
    } else {
      tv[2] = v;     ti[2] = id;
    }
  }
}

// Merge-phase insert: ids arrive out of order -> full tie-aware total order.
__device__ __forceinline__ void insert_merge(float v, int id, float tv[3], int ti[3]) {
  if (v > tv[2] || (v == tv[2] && id < ti[2])) {
    if (v > tv[0] || (v == tv[0] && id < ti[0])) {
      tv[2] = tv[1]; ti[2] = ti[1];
      tv[1] = tv[0]; ti[1] = ti[0];
      tv[0] = v;     ti[0] = id;
    } else if (v > tv[1] || (v == tv[1] && id < ti[1])) {
      tv[2] = tv[1]; ti[2] = ti[1];
      tv[1] = v;     ti[1] = id;
    } else {
      tv[2] = v;     ti[2] = id;
    }
  }
}

// Butterfly merge of per-lane top-3 lists across the 64-lane wave.
__device__ __forceinline__ void wave_merge3(float tv[3], int ti[3]) {
  #pragma unroll
  for (int m = 1; m < 64; m <<= 1) {
    float v0 = __shfl_xor(tv[0], m, 64); int i0 = __shfl_xor(ti[0], m, 64);
    float v1 = __shfl_xor(tv[1], m, 64); int i1 = __shfl_xor(ti[1], m, 64);
    float v2 = __shfl_xor(tv[2], m, 64); int i2 = __shfl_xor(ti[2], m, 64);
    insert_merge(v0, i0, tv, ti);
    insert_merge(v1, i1, tv, ti);
    insert_merge(v2, i2, tv, ti);
  }
}

__device__ __forceinline__ float wave_sum(float x) {
  #pragma unroll
  for (int m = 1; m < 64; m <<= 1) x += __shfl_xor(x, m, 64);
  return x;
}

// ---------------------------------------------------------------------------
// Fused kernel, 2048 blocks x 512 threads.
//   blocks 0..1023    : overlaps write + top-3 + sum for bs = gb
//   blocks 1024..2047 : props_feats gather for bs = gb - 1024
// Gather blocks tail-fill CUs as stream blocks retire. scores loads are
// NON-TEMPORAL: the 268 MB stream has zero reuse (once per replay, self-
// thrashing across replays), so skipping L3 allocation keeps the 33 MB
// frames array L3-resident across replays instead.
// ---------------------------------------------------------------------------
__global__ __launch_bounds__(512, 8) void fused_kernel(
    const float* __restrict__ frames, const float* __restrict__ props,
    const float* __restrict__ duration, const float* __restrict__ yt,
    const float* __restrict__ scores, float* __restrict__ out) {
  int gb = blockIdx.x;
  int tid = threadIdx.x;

  if (gb >= 1024) {
    // ---------------- props_feats gather (tail blocks) ----------------
    int bs = gb - 1024;
    int b = bs >> 4;
    float dur = duration[b];
    float p0 = props[bs * 2 + 0];
    float p1 = props[bs * 2 + 1];
    int s_fr = (int)(p0 / dur * 256.0f); if (s_fr > 255) s_fr = 255;
    int e_fr = (int)(p1 / dur * 256.0f); if (e_fr > 255) e_fr = 255;
    bool zp = (p0 == 0.0f) && (p1 == 0.0f) && (dur == 0.0f);
    float sf = (float)s_fr;
    float df = (float)(e_fr - s_fr);
    const f32x4* f4 = (const f32x4*)frames + (long)b * (256L * 125L);
    f32x4* o4 = (f32x4*)out + OUT0 / 4 + (long)bs * (16L * 125L);
    for (int k = tid; k < 2000; k += 512) {
      int f = k / 125;            // frame step 0..15
      int w = k - f * 125;        // float4 within row
      float lin = sf + ((float)f * df) * (1.0f / 16.0f);   // exact: integral
      int idx = (int)lin; if (idx > 255) idx = 255; if (idx < 0) idx = 0;
      f32x4 v = f4[(long)idx * 125 + w];   // normal load: wants L3 residency
      if (zp) v = (f32x4){0.0f, 0.0f, 0.0f, 0.0f};
      __builtin_nontemporal_store(v, &o4[k]);
    }
    return;
  }

  // ---------------- overlaps + top-3 + sum (stream blocks) ----------------
  __shared__ float swv[24];
  __shared__ int   swi[24];
  __shared__ float swsum[8];

  int bs = gb;              // b*16+s
  int b = bs >> 4;
  float dur = duration[b];
  float gs = yt[bs * 2 + 0];
  float ge = yt[bs * 2 + 1];
  bool gz = (gs == 0.0f) && (ge == 0.0f);
  const float inv256 = 1.0f / 256.0f;   // exact pow2: x*inv256 == x/256

  // per-thread loop invariants (column j fixed: k&63 == tid&63)
  int j = (tid & 63) << 2;
  float pe1 = (float)(j + 1) * dur * inv256;
  float pe2 = (float)(j + 2) * dur * inv256;
  float pe3 = (float)(j + 3) * dur * inv256;
  float pe4 = (float)(j + 4) * dur * inv256;
  float mn1 = fminf(pe1, ge), mx1 = fmaxf(pe1, ge);
  float mn2 = fminf(pe2, ge), mx2 = fmaxf(pe2, ge);
  float mn3 = fminf(pe3, ge), mx3 = fmaxf(pe3, ge);
  float mn4 = fminf(pe4, ge), mx4 = fmaxf(pe4, ge);

  const f32x4* s4 = (const f32x4*)scores + (long)bs * 16384L;
  f32x4* o4 = (f32x4*)out + OUT1 / 4 + (long)bs * 16384L;

  float tv[3] = {-FLT_MAX, -FLT_MAX, -FLT_MAX};
  int   ti[3] = {0x7fffffff, 0x7fffffff, 0x7fffffff};
  float lsum = 0.0f;

#define OVROW(K)                                                          \
  {                                                                       \
    int i = (K) >> 6;                                                     \
    float ps = (float)i * dur * inv256;                                   \
    float pmg = fmaxf(ps, gs);                                            \
    float pmn = fminf(ps, gs);                                            \
    f32x4 ov;                                                             \
    ov.x = gz ? 0.0f : fmaxf(0.0f, mn1 - pmg) *                           \
                       __builtin_amdgcn_rcpf(fmaxf(0.0f, mx1 - pmn) + 1e-6f); \
    ov.y = gz ? 0.0f : fmaxf(0.0f, mn2 - pmg) *                           \
                       __builtin_amdgcn_rcpf(fmaxf(0.0f, mx2 - pmn) + 1e-6f); \
    ov.z = gz ? 0.0f : fmaxf(0.0f, mn3 - pmg) *                           \
                       __builtin_amdgcn_rcpf(fmaxf(0.0f, mx3 - pmn) + 1e-6f); \
    ov.w = gz ? 0.0f : fmaxf(0.0f, mn4 - pmg) *                           \
                       __builtin_amdgcn_rcpf(fmaxf(0.0f, mx4 - pmn) + 1e-6f); \
    __builtin_nontemporal_store(ov, &o4[K]);                              \
  }

#define TOPK4(SC, K)                                                      \
  {                                                                       \
    int fidx = (K) << 2;                                                  \
    insert_stream(SC.x, fidx + 0, tv, ti);                                \
    insert_stream(SC.y, fidx + 1, tv, ti);                                \
    insert_stream(SC.z, fidx + 2, tv, ti);                                \
    insert_stream(SC.w, fidx + 3, tv, ti);                                \
    lsum += SC.x + SC.y + SC.z + SC.w;                                    \
  }

  // Per step: 4 NT loads, then 4 index-only stores (independent of loads,
  // write index skewed by XOR 8192 = bijection on [0,16384)), then the 4
  // topk updates that consume the loads.
  for (int it = 0; it < 32; it += 4) {
    int k0 = it * 512 + tid;
    int k1 = k0 + 512;
    int k2 = k0 + 1024;
    int k3 = k0 + 1536;
    f32x4 a = __builtin_nontemporal_load(&s4[k0]);
    f32x4 c = __builtin_nontemporal_load(&s4[k1]);
    f32x4 d = __builtin_nontemporal_load(&s4[k2]);
    f32x4 e = __builtin_nontemporal_load(&s4[k3]);
    OVROW(k0 ^ 8192);
    OVROW(k1 ^ 8192);
    OVROW(k2 ^ 8192);
    OVROW(k3 ^ 8192);
    TOPK4(a, k0);
    TOPK4(c, k1);
    TOPK4(d, k2);
    TOPK4(e, k3);
  }
#undef OVROW
#undef TOPK4

  // wave-level reductions (barrier-free), then one cross-wave merge
  wave_merge3(tv, ti);
  lsum = wave_sum(lsum);
  int wave = tid >> 6;
  if ((tid & 63) == 0) {
    swv[wave * 3 + 0] = tv[0]; swi[wave * 3 + 0] = ti[0];
    swv[wave * 3 + 1] = tv[1]; swi[wave * 3 + 1] = ti[1];
    swv[wave * 3 + 2] = tv[2]; swi[wave * 3 + 2] = ti[2];
    swsum[wave] = lsum;
  }
  __syncthreads();

  if (tid == 0) {
    float fv[3] = {-FLT_MAX, -FLT_MAX, -FLT_MAX};
    int   fi[3] = {0x7fffffff, 0x7fffffff, 0x7fffffff};
    #pragma unroll
    for (int t = 0; t < 24; ++t) insert_merge(swv[t], swi[t], fv, fi);
    float total = 0.0f;
    #pragma unroll
    for (int w = 0; w < 8; ++w) total += swsum[w];
    bool valid = total > 0.001f;
    float* o2 = out + OUT2 + (long)bs * 6;
    float* o3 = out + OUT3 + (long)bs * 3;
    #pragma unroll
    for (int r = 0; r < 3; ++r) {
      float pi = (float)(fi[r] >> 8);     // top_idx // N
      float pj = (float)(fi[r] & 255);    // top_idx % N
      o3[r]         = valid ? fv[r] : 0.0f;
      o2[r * 2 + 0] = valid ? (pi * inv256) * dur : 0.0f;
      o2[r * 2 + 1] = valid ? (pj * inv256) * dur : 0.0f;
    }
  }
}

extern "C" void kernel_launch(void* const* d_in, const int* in_sizes, int n_in,
                              void* d_out, int out_size, void* d_ws, size_t ws_size,
                              hipStream_t stream) {
  const float* frames   = (const float*)d_in[0];  // (64,256,500)
  const float* props    = (const float*)d_in[1];  // (64,16,2)
  const float* duration = (const float*)d_in[2];  // (64,)
  const float* yt       = (const float*)d_in[3];  // (64,16,1,2)
  const float* scores   = (const float*)d_in[4];  // (64,16,1,256,256)
  float* out = (float*)d_out;

  hipLaunchKernelGGL(fused_kernel, dim3(2048), dim3(512), 0, stream,
                     frames, props, duration, yt, scores, out);
}

// Round 11
// 102.924 us; speedup vs baseline: 1.1374x; 1.1374x over previous
//
#include <hip/hip_runtime.h>
#include <float.h>

typedef float f32x4 __attribute__((ext_vector_type(4)));  // native vec for NT ops

// Problem constants (B=64, S=16, N=256, T=256, D=500, NUM_FRAMES=16, TOPK=3)
static constexpr long OUT0 = 0;          // props_feats  (1024, 16, 500)  = 8,192,000
static constexpr long OUT1 = 8192000;    // overlaps     (64,16,256,256)  = 67,108,864
static constexpr long OUT2 = 75300864;   // max_timestamps (64,16,3,2)    = 6,144
static constexpr long OUT3 = 75307008;   // max_scores   (64,16,3)        = 3,072

// Streaming-phase insert: ids strictly increase within a thread, so the
// lax.top_k tie-break (equal value -> smaller index) is automatic.
__device__ __forceinline__ void insert_stream(float v, int id, float tv[3], int ti[3]) {
  if (v > tv[2]) {
    if (v > tv[0]) {
      tv[2] = tv[1]; ti[2] = ti[1];
      tv[1] = tv[0]; ti[1] = ti[0];
      tv[0] = v;     ti[0] = id;
    } else if (v > tv[1]) {
      tv[2] = tv[1]; ti[2] = ti[1];
      tv[1] = v;     ti[1] = id;
    } else {
      tv[2] = v;     ti[2] = id;
    }
  }
}

// Merge-phase insert: ids arrive out of order -> full tie-aware total order.
__device__ __forceinline__ void insert_merge(float v, int id, float tv[3], int ti[3]) {
  if (v > tv[2] || (v == tv[2] && id < ti[2])) {
    if (v > tv[0] || (v == tv[0] && id < ti[0])) {
      tv[2] = tv[1]; ti[2] = ti[1];
      tv[1] = tv[0]; ti[1] = ti[0];
      tv[0] = v;     ti[0] = id;
    } else if (v > tv[1] || (v == tv[1] && id < ti[1])) {
      tv[2] = tv[1]; ti[2] = ti[1];
      tv[1] = v;     ti[1] = id;
    } else {
      tv[2] = v;     ti[2] = id;
    }
  }
}

// Butterfly merge of per-lane top-3 lists across the 64-lane wave.
__device__ __forceinline__ void wave_merge3(float tv[3], int ti[3]) {
  #pragma unroll
  for (int m = 1; m < 64; m <<= 1) {
    float v0 = __shfl_xor(tv[0], m, 64); int i0 = __shfl_xor(ti[0], m, 64);
    float v1 = __shfl_xor(tv[1], m, 64); int i1 = __shfl_xor(ti[1], m, 64);
    float v2 = __shfl_xor(tv[2], m, 64); int i2 = __shfl_xor(ti[2], m, 64);
    insert_merge(v0, i0, tv, ti);
    insert_merge(v1, i1, tv, ti);
    insert_merge(v2, i2, tv, ti);
  }
}

__device__ __forceinline__ float wave_sum(float x) {
  #pragma unroll
  for (int m = 1; m < 64; m <<= 1) x += __shfl_xor(x, m, 64);
  return x;
}

// ---------------------------------------------------------------------------
// Fused kernel, 2048 blocks x 512 threads.
//   blocks 0..1023    : overlaps write + top-3 + sum for bs = gb
//   blocks 1024..2047 : props_feats gather for bs = gb - 1024
// Only ~1024 blocks are resident at once (8 waves x 4 blocks/CU), so the
// gather blocks tail-fill CUs as stream blocks retire -> kernel A's ~11 us
// rides the tail instead of serializing after kernel B.
// scores loads are NORMAL (R10 ablation: NT loads cost +14 us).
// ---------------------------------------------------------------------------
__global__ __launch_bounds__(512, 8) void fused_kernel(
    const float* __restrict__ frames, const float* __restrict__ props,
    const float* __restrict__ duration, const float* __restrict__ yt,
    const float* __restrict__ scores, float* __restrict__ out) {
  int gb = blockIdx.x;
  int tid = threadIdx.x;

  if (gb >= 1024) {
    // ---------------- props_feats gather (tail blocks) ----------------
    int bs = gb - 1024;
    int b = bs >> 4;
    float dur = duration[b];
    float p0 = props[bs * 2 + 0];
    float p1 = props[bs * 2 + 1];
    int s_fr = (int)(p0 / dur * 256.0f); if (s_fr > 255) s_fr = 255;
    int e_fr = (int)(p1 / dur * 256.0f); if (e_fr > 255) e_fr = 255;
    bool zp = (p0 == 0.0f) && (p1 == 0.0f) && (dur == 0.0f);
    float sf = (float)s_fr;
    float df = (float)(e_fr - s_fr);
    const f32x4* f4 = (const f32x4*)frames + (long)b * (256L * 125L);
    f32x4* o4 = (f32x4*)out + OUT0 / 4 + (long)bs * (16L * 125L);
    for (int k = tid; k < 2000; k += 512) {
      int f = k / 125;            // frame step 0..15
      int w = k - f * 125;        // float4 within row
      float lin = sf + ((float)f * df) * (1.0f / 16.0f);   // exact: integral
      int idx = (int)lin; if (idx > 255) idx = 255; if (idx < 0) idx = 0;
      f32x4 v = f4[(long)idx * 125 + w];
      if (zp) v = (f32x4){0.0f, 0.0f, 0.0f, 0.0f};
      __builtin_nontemporal_store(v, &o4[k]);
    }
    return;
  }

  // ---------------- overlaps + top-3 + sum (stream blocks) ----------------
  __shared__ float swv[24];
  __shared__ int   swi[24];
  __shared__ float swsum[8];

  int bs = gb;              // b*16+s
  int b = bs >> 4;
  float dur = duration[b];
  float gs = yt[bs * 2 + 0];
  float ge = yt[bs * 2 + 1];
  bool gz = (gs == 0.0f) && (ge == 0.0f);
  const float inv256 = 1.0f / 256.0f;   // exact pow2: x*inv256 == x/256

  // per-thread loop invariants (column j fixed: k&63 == tid&63)
  int j = (tid & 63) << 2;
  float pe1 = (float)(j + 1) * dur * inv256;
  float pe2 = (float)(j + 2) * dur * inv256;
  float pe3 = (float)(j + 3) * dur * inv256;
  float pe4 = (float)(j + 4) * dur * inv256;
  float mn1 = fminf(pe1, ge), mx1 = fmaxf(pe1, ge);
  float mn2 = fminf(pe2, ge), mx2 = fmaxf(pe2, ge);
  float mn3 = fminf(pe3, ge), mx3 = fmaxf(pe3, ge);
  float mn4 = fminf(pe4, ge), mx4 = fmaxf(pe4, ge);

  const f32x4* s4 = (const f32x4*)scores + (long)bs * 16384L;
  f32x4* o4 = (f32x4*)out + OUT1 / 4 + (long)bs * 16384L;

  float tv[3] = {-FLT_MAX, -FLT_MAX, -FLT_MAX};
  int   ti[3] = {0x7fffffff, 0x7fffffff, 0x7fffffff};
  float lsum = 0.0f;

#define OVROW(K)                                                          \
  {                                                                       \
    int i = (K) >> 6;                                                     \
    float ps = (float)i * dur * inv256;                                   \
    float pmg = fmaxf(ps, gs);                                            \
    float pmn = fminf(ps, gs);                                            \
    f32x4 ov;                                                             \
    ov.x = gz ? 0.0f : fmaxf(0.0f, mn1 - pmg) *                           \
                       __builtin_amdgcn_rcpf(fmaxf(0.0f, mx1 - pmn) + 1e-6f); \
    ov.y = gz ? 0.0f : fmaxf(0.0f, mn2 - pmg) *                           \
                       __builtin_amdgcn_rcpf(fmaxf(0.0f, mx2 - pmn) + 1e-6f); \
    ov.z = gz ? 0.0f : fmaxf(0.0f, mn3 - pmg) *                           \
                       __builtin_amdgcn_rcpf(fmaxf(0.0f, mx3 - pmn) + 1e-6f); \
    ov.w = gz ? 0.0f : fmaxf(0.0f, mn4 - pmg) *                           \
                       __builtin_amdgcn_rcpf(fmaxf(0.0f, mx4 - pmn) + 1e-6f); \
    __builtin_nontemporal_store(ov, &o4[K]);                              \
  }

#define TOPK4(SC, K)                                                      \
  {                                                                       \
    int fidx = (K) << 2;                                                  \
    insert_stream(SC.x, fidx + 0, tv, ti);                                \
    insert_stream(SC.y, fidx + 1, tv, ti);                                \
    insert_stream(SC.z, fidx + 2, tv, ti);                                \
    insert_stream(SC.w, fidx + 3, tv, ti);                                \
    lsum += SC.x + SC.y + SC.z + SC.w;                                    \
  }

  // Per step: 4 loads, then 4 index-only stores (independent of the loads,
  // write index skewed by XOR 8192 = bijection on [0,16384)), then the 4
  // topk updates that consume the loads.
  for (int it = 0; it < 32; it += 4) {
    int k0 = it * 512 + tid;
    int k1 = k0 + 512;
    int k2 = k0 + 1024;
    int k3 = k0 + 1536;
    f32x4 a = s4[k0];
    f32x4 c = s4[k1];
    f32x4 d = s4[k2];
    f32x4 e = s4[k3];
    OVROW(k0 ^ 8192);
    OVROW(k1 ^ 8192);
    OVROW(k2 ^ 8192);
    OVROW(k3 ^ 8192);
    TOPK4(a, k0);
    TOPK4(c, k1);
    TOPK4(d, k2);
    TOPK4(e, k3);
  }
#undef OVROW
#undef TOPK4

  // wave-level reductions (barrier-free), then one cross-wave merge
  wave_merge3(tv, ti);
  lsum = wave_sum(lsum);
  int wave = tid >> 6;
  if ((tid & 63) == 0) {
    swv[wave * 3 + 0] = tv[0]; swi[wave * 3 + 0] = ti[0];
    swv[wave * 3 + 1] = tv[1]; swi[wave * 3 + 1] = ti[1];
    swv[wave * 3 + 2] = tv[2]; swi[wave * 3 + 2] = ti[2];
    swsum[wave] = lsum;
  }
  __syncthreads();

  if (tid == 0) {
    float fv[3] = {-FLT_MAX, -FLT_MAX, -FLT_MAX};
    int   fi[3] = {0x7fffffff, 0x7fffffff, 0x7fffffff};
    #pragma unroll
    for (int t = 0; t < 24; ++t) insert_merge(swv[t], swi[t], fv, fi);
    float total = 0.0f;
    #pragma unroll
    for (int w = 0; w < 8; ++w) total += swsum[w];
    bool valid = total > 0.001f;
    float* o2 = out + OUT2 + (long)bs * 6;
    float* o3 = out + OUT3 + (long)bs * 3;
    #pragma unroll
    for (int r = 0; r < 3; ++r) {
      float pi = (float)(fi[r] >> 8);     // top_idx // N
      float pj = (float)(fi[r] & 255);    // top_idx % N
      o3[r]         = valid ? fv[r] : 0.0f;
      o2[r * 2 + 0] = valid ? (pi * inv256) * dur : 0.0f;
      o2[r * 2 + 1] = valid ? (pj * inv256) * dur : 0.0f;
    }
  }
}

extern "C" void kernel_launch(void* const* d_in, const int* in_sizes, int n_in,
                              void* d_out, int out_size, void* d_ws, size_t ws_size,
                              hipStream_t stream) {
  const float* frames   = (const float*)d_in[0];  // (64,256,500)
  const float* props    = (const float*)d_in[1];  // (64,16,2)
  const float* duration = (const float*)d_in[2];  // (64,)
  const float* yt       = (const float*)d_in[3];  // (64,16,1,2)
  const float* scores   = (const float*)d_in[4];  // (64,16,1,256,256)
  float* out = (float*)d_out;

  hipLaunchKernelGGL(fused_kernel, dim3(2048), dim3(512), 0, stream,
                     frames, props, duration, yt, scores, out);
}